// Round 1
// 559.146 us; speedup vs baseline: 1.0182x; 1.0182x over previous
//
#include <hip/hip_runtime.h>

// Level-phased multiresolution hash-grid embedding.
// Round-4: kernel A (gather, 358 us, request-rate bound) left byte-identical.
// Kernel B rewritten: the old version ran at ~1.2 TB/s effective (~210 us for
// 256 MB of traffic) due to nontemporal strided reads + 16B/lane stride-128
// stores (64 partial line-touches per wave-store). New B stages 256 points x
// 16 levels in LDS (stride-17 float2 padding -> bank-minimal both phases) and
// writes 32 KB of fully-contiguous output per block (1 KB per wave-store).

#define TSIZE (1u << 19)
#define HMASK (TSIZE - 1u)
#define P1 2654435761u
#define P2 805459861u

typedef float f32x4 __attribute__((ext_vector_type(4)));
typedef float f32x2 __attribute__((ext_vector_type(2)));

__constant__ float RES_C[16] = {16.f, 20.f, 25.f, 32.f, 40.f, 50.f, 64.f, 80.f,
                                101.f, 128.f, 161.f, 203.f, 256.f, 322.f, 406.f, 512.f};

// ---------------- Kernel A: one level per block, 2 points per thread ----------------
// UNCHANGED from round-3 (measured 358 us, occupancy 86%, the L2-locality win).
__global__ __launch_bounds__(256) void gather_level_kernel(
    const float* __restrict__ x,
    const float* __restrict__ tables,
    f32x2* __restrict__ ws,          // [16][npoints] float2
    int npoints, int levelShift)
{
    const int level = blockIdx.x >> levelShift;              // slow index -> phases
    const int chunk = blockIdx.x & ((1 << levelShift) - 1);
    const float halfr = 0.5f * RES_C[level];                 // 1/grid, exact

    const float2* __restrict__ tab = (const float2*)tables + (size_t)level * TSIZE;
    f32x2* __restrict__ wrow = ws + (size_t)level * npoints;

#pragma unroll
    for (int q = 0; q < 2; ++q) {
        const int p = chunk * 512 + q * 256 + threadIdx.x;
        if (p >= npoints) break;

        const float fx = (x[3 * p + 0] + 1.0f) * halfr;
        const float fy = (x[3 * p + 1] + 1.0f) * halfr;
        const float fz = (x[3 * p + 2] + 1.0f) * halfr;

        const float bx = floorf(fx);
        const float by = floorf(fy);
        const float bz = floorf(fz);

        const float wx = fx - bx;
        const float wy = fy - by;
        const float wz = fz - bz;

        const unsigned ix0 = (unsigned)(int)bx;              // * prime 1
        const unsigned iy0 = (unsigned)(int)by * P1;
        const unsigned iz0 = (unsigned)(int)bz * P2;
        const unsigned ix1 = ix0 + 1u;
        const unsigned iy1 = iy0 + P1;
        const unsigned iz1 = iz0 + P2;

        const float2 v000 = tab[(ix0 ^ iy0 ^ iz0) & HMASK];
        const float2 v001 = tab[(ix0 ^ iy0 ^ iz1) & HMASK];
        const float2 v010 = tab[(ix0 ^ iy1 ^ iz0) & HMASK];
        const float2 v011 = tab[(ix0 ^ iy1 ^ iz1) & HMASK];
        const float2 v100 = tab[(ix1 ^ iy0 ^ iz0) & HMASK];
        const float2 v101 = tab[(ix1 ^ iy0 ^ iz1) & HMASK];
        const float2 v110 = tab[(ix1 ^ iy1 ^ iz0) & HMASK];
        const float2 v111 = tab[(ix1 ^ iy1 ^ iz1) & HMASK];

        const float c00a = v000.x + wx * (v100.x - v000.x);
        const float c00b = v000.y + wx * (v100.y - v000.y);
        const float c01a = v001.x + wx * (v101.x - v001.x);
        const float c01b = v001.y + wx * (v101.y - v001.y);
        const float c10a = v010.x + wx * (v110.x - v010.x);
        const float c10b = v010.y + wx * (v110.y - v010.y);
        const float c11a = v011.x + wx * (v111.x - v011.x);
        const float c11b = v011.y + wx * (v111.y - v011.y);

        const float c0a = c00a + wy * (c10a - c00a);
        const float c0b = c00b + wy * (c10b - c00b);
        const float c1a = c01a + wy * (c11a - c01a);
        const float c1b = c01b + wy * (c11b - c01b);

        f32x2 r = { c0a + wz * (c1a - c0a), c0b + wz * (c1b - c0b) };
        // 64 lanes x 8 B contiguous = full 64 B lines per instruction:
        // nontemporal keeps the ws stream from evicting the hot table in L2.
        __builtin_nontemporal_store(r, wrow + p);
    }
}

// ---------------- Kernel B: LDS-staged transpose [16][N][2] -> [N][32] ----------------
// Both sides fully coalesced:
//   loads : 16 wave-loads x 512 B contiguous per wave
//   stores: 8 wave-stores x 1 KB contiguous per wave (32 KB contiguous / block)
// LDS tile [256][17] float2: stride 17 makes both the level-major write phase
// and the point-major read phase hit the 4-cycle (512 B / 128 B-per-cycle)
// bank floor -- no excess conflicts.
__global__ __launch_bounds__(256) void transpose_lds_kernel(
    const f32x2* __restrict__ ws,
    float* __restrict__ out,
    int npoints)
{
    __shared__ f32x2 tile[256][17];   // 34,816 B -> 4 blocks/CU by LDS
    const int t = threadIdx.x;
    const int base = blockIdx.x * 256;

    if (base + 256 <= npoints) {
#pragma unroll
        for (int l = 0; l < 16; ++l)
            tile[t][l] = ws[(size_t)l * npoints + base + t];
        __syncthreads();

        f32x4* __restrict__ o = (f32x4*)(out + (size_t)base * 32);
#pragma unroll
        for (int k = 0; k < 8; ++k) {
            const int s = (k << 8) | t;   // xmm index within the block's 32 KB
            const int p = s >> 3;         // local point
            const int c = s & 7;          // 16 B chunk within the point's row
            const f32x2 a = tile[p][2 * c];
            const f32x2 b = tile[p][2 * c + 1];
            f32x4 q = { a.x, a.y, b.x, b.y };
            o[s] = q;
        }
    } else {
        // tail (npoints not a multiple of 256): per-point guarded path
        const int p = base + t;
        if (p < npoints) {
            f32x2 v[16];
#pragma unroll
            for (int l = 0; l < 16; ++l)
                v[l] = ws[(size_t)l * npoints + p];
            f32x4* orow = (f32x4*)(out + (size_t)p * 32);
#pragma unroll
            for (int i = 0; i < 8; ++i) {
                f32x4 q = { v[2 * i].x, v[2 * i].y, v[2 * i + 1].x, v[2 * i + 1].y };
                orow[i] = q;
            }
        }
    }
}

// ---------------- Fallback (round-3 kernel) if ws too small ----------------
__global__ __launch_bounds__(256) void hashgrid_fallback_kernel(
    const float* __restrict__ x,
    const float* __restrict__ tables,
    float* __restrict__ out)
{
    const int p = blockIdx.x * 256 + threadIdx.x;

    const float px = x[3 * p + 0] + 1.0f;
    const float py = x[3 * p + 1] + 1.0f;
    const float pz = x[3 * p + 2] + 1.0f;

    float acc[32];
    const float2* __restrict__ tab = (const float2*)tables;

#pragma unroll
    for (int l = 0; l < 16; ++l) {
        const float halfr = 0.5f * RES_C[l];
        const float fx = px * halfr, fy = py * halfr, fz = pz * halfr;
        const float bx = floorf(fx), by = floorf(fy), bz = floorf(fz);
        const float wx = fx - bx, wy = fy - by, wz = fz - bz;

        const unsigned ix0 = (unsigned)(int)bx;
        const unsigned iy0 = (unsigned)(int)by * P1;
        const unsigned iz0 = (unsigned)(int)bz * P2;
        const unsigned ix1 = ix0 + 1u, iy1 = iy0 + P1, iz1 = iz0 + P2;
        const unsigned base = (unsigned)l * TSIZE;

        const float2 v000 = tab[base + ((ix0 ^ iy0 ^ iz0) & HMASK)];
        const float2 v001 = tab[base + ((ix0 ^ iy0 ^ iz1) & HMASK)];
        const float2 v010 = tab[base + ((ix0 ^ iy1 ^ iz0) & HMASK)];
        const float2 v011 = tab[base + ((ix0 ^ iy1 ^ iz1) & HMASK)];
        const float2 v100 = tab[base + ((ix1 ^ iy0 ^ iz0) & HMASK)];
        const float2 v101 = tab[base + ((ix1 ^ iy0 ^ iz1) & HMASK)];
        const float2 v110 = tab[base + ((ix1 ^ iy1 ^ iz0) & HMASK)];
        const float2 v111 = tab[base + ((ix1 ^ iy1 ^ iz1) & HMASK)];

        const float c00a = v000.x + wx * (v100.x - v000.x);
        const float c00b = v000.y + wx * (v100.y - v000.y);
        const float c01a = v001.x + wx * (v101.x - v001.x);
        const float c01b = v001.y + wx * (v101.y - v001.y);
        const float c10a = v010.x + wx * (v110.x - v010.x);
        const float c10b = v010.y + wx * (v110.y - v010.y);
        const float c11a = v011.x + wx * (v111.x - v011.x);
        const float c11b = v011.y + wx * (v111.y - v011.y);

        const float c0a = c00a + wy * (c10a - c00a);
        const float c0b = c00b + wy * (c10b - c00b);
        const float c1a = c01a + wy * (c11a - c01a);
        const float c1b = c01b + wy * (c11b - c01b);

        acc[2 * l + 0] = c0a + wz * (c1a - c0a);
        acc[2 * l + 1] = c0b + wz * (c1b - c0b);
    }

    f32x4* orow = (f32x4*)(out + (size_t)p * 32);
#pragma unroll
    for (int i = 0; i < 8; ++i) {
        f32x4 v = { acc[4 * i + 0], acc[4 * i + 1], acc[4 * i + 2], acc[4 * i + 3] };
        orow[i] = v;
    }
}

extern "C" void kernel_launch(void* const* d_in, const int* in_sizes, int n_in,
                              void* d_out, int out_size, void* d_ws, size_t ws_size,
                              hipStream_t stream) {
    const float* x      = (const float*)d_in[0];
    const float* tables = (const float*)d_in[1];
    float* out          = (float*)d_out;

    const int npoints = in_sizes[0] / 3;                       // 1048576
    const size_t ws_needed = (size_t)16 * npoints * sizeof(float2);  // 128 MB

    if (ws_size >= ws_needed) {
        // chunks per level: ceil(npoints/512) rounded up to power of two
        int chunks = (npoints + 511) / 512;
        int levelShift = 0;
        while ((1 << levelShift) < chunks) ++levelShift;

        dim3 blockA(256);
        dim3 gridA(16 << levelShift);
        hipLaunchKernelGGL(gather_level_kernel, gridA, blockA, 0, stream,
                           x, tables, (f32x2*)d_ws, npoints, levelShift);

        dim3 blockB(256);
        dim3 gridB((npoints + 255) / 256);
        hipLaunchKernelGGL(transpose_lds_kernel, gridB, blockB, 0, stream,
                           (const f32x2*)d_ws, out, npoints);
    } else {
        dim3 block(256);
        dim3 grid((npoints + 255) / 256);
        hipLaunchKernelGGL(hashgrid_fallback_kernel, grid, block, 0, stream,
                           x, tables, out);
    }
}

// Round 2
// 537.995 us; speedup vs baseline: 1.0582x; 1.0393x over previous
//
#include <hip/hip_runtime.h>

// Level-phased multiresolution hash-grid embedding.
// Round-5: A's ws stores made PLAIN (allocate L2 -> flushed to Infinity Cache
// at kernel end; ws=128MB fits the 256MB IC). Round-1 showed B's ~200us was
// not a coalescing problem (LDS-staged B changed nothing): A's nontemporal ws
// stores were pushing ws all the way to HBM, so B re-read 128MB cold. Now ws
// should be IC-resident for B. B's out stores become nontemporal so the
// write-only out stream does not evict ws from the IC while B runs.

#define TSIZE (1u << 19)
#define HMASK (TSIZE - 1u)
#define P1 2654435761u
#define P2 805459861u

typedef float f32x4 __attribute__((ext_vector_type(4)));
typedef float f32x2 __attribute__((ext_vector_type(2)));

__constant__ float RES_C[16] = {16.f, 20.f, 25.f, 32.f, 40.f, 50.f, 64.f, 80.f,
                                101.f, 128.f, 161.f, 203.f, 256.f, 322.f, 406.f, 512.f};

// ---------------- Kernel A: one level per block, 2 points per thread ----------------
// Identical to round-3/4 except the ws store is a PLAIN store (L2->IC), not nt.
__global__ __launch_bounds__(256) void gather_level_kernel(
    const float* __restrict__ x,
    const float* __restrict__ tables,
    f32x2* __restrict__ ws,          // [16][npoints] float2
    int npoints, int levelShift)
{
    const int level = blockIdx.x >> levelShift;              // slow index -> phases
    const int chunk = blockIdx.x & ((1 << levelShift) - 1);
    const float halfr = 0.5f * RES_C[level];                 // 1/grid, exact

    const float2* __restrict__ tab = (const float2*)tables + (size_t)level * TSIZE;
    f32x2* __restrict__ wrow = ws + (size_t)level * npoints;

#pragma unroll
    for (int q = 0; q < 2; ++q) {
        const int p = chunk * 512 + q * 256 + threadIdx.x;
        if (p >= npoints) break;

        const float fx = (x[3 * p + 0] + 1.0f) * halfr;
        const float fy = (x[3 * p + 1] + 1.0f) * halfr;
        const float fz = (x[3 * p + 2] + 1.0f) * halfr;

        const float bx = floorf(fx);
        const float by = floorf(fy);
        const float bz = floorf(fz);

        const float wx = fx - bx;
        const float wy = fy - by;
        const float wz = fz - bz;

        const unsigned ix0 = (unsigned)(int)bx;              // * prime 1
        const unsigned iy0 = (unsigned)(int)by * P1;
        const unsigned iz0 = (unsigned)(int)bz * P2;
        const unsigned ix1 = ix0 + 1u;
        const unsigned iy1 = iy0 + P1;
        const unsigned iz1 = iz0 + P2;

        const float2 v000 = tab[(ix0 ^ iy0 ^ iz0) & HMASK];
        const float2 v001 = tab[(ix0 ^ iy0 ^ iz1) & HMASK];
        const float2 v010 = tab[(ix0 ^ iy1 ^ iz0) & HMASK];
        const float2 v011 = tab[(ix0 ^ iy1 ^ iz1) & HMASK];
        const float2 v100 = tab[(ix1 ^ iy0 ^ iz0) & HMASK];
        const float2 v101 = tab[(ix1 ^ iy0 ^ iz1) & HMASK];
        const float2 v110 = tab[(ix1 ^ iy1 ^ iz0) & HMASK];
        const float2 v111 = tab[(ix1 ^ iy1 ^ iz1) & HMASK];

        const float c00a = v000.x + wx * (v100.x - v000.x);
        const float c00b = v000.y + wx * (v100.y - v000.y);
        const float c01a = v001.x + wx * (v101.x - v001.x);
        const float c01b = v001.y + wx * (v101.y - v001.y);
        const float c10a = v010.x + wx * (v110.x - v010.x);
        const float c10b = v010.y + wx * (v110.y - v010.y);
        const float c11a = v011.x + wx * (v111.x - v011.x);
        const float c11b = v011.y + wx * (v111.y - v011.y);

        const float c0a = c00a + wy * (c10a - c00a);
        const float c0b = c00b + wy * (c10b - c00b);
        const float c1a = c01a + wy * (c11a - c01a);
        const float c1b = c01b + wy * (c11b - c01b);

        f32x2 r = { c0a + wz * (c1a - c0a), c0b + wz * (c1b - c0b) };
        // PLAIN store: allocate in L2, flushed to Infinity Cache at kernel end.
        // ws (128 MB) fits the 256 MB IC -> kernel B reads it from IC, not HBM.
        wrow[p] = r;
    }
}

// ---------------- Kernel B: LDS-staged transpose [16][N][2] -> [N][32] ----------------
// loads : nontemporal (ws line touched exactly once; no L2 pollution)
// stores: nontemporal (out is write-only; keep the 128 MB stream from
//         evicting ws out of the Infinity Cache while B runs)
__global__ __launch_bounds__(256) void transpose_lds_kernel(
    const f32x2* __restrict__ ws,
    float* __restrict__ out,
    int npoints)
{
    __shared__ f32x2 tile[256][17];   // 34,816 B -> 4 blocks/CU by LDS
    const int t = threadIdx.x;
    const int base = blockIdx.x * 256;

    if (base + 256 <= npoints) {
#pragma unroll
        for (int l = 0; l < 16; ++l)
            tile[t][l] = __builtin_nontemporal_load(ws + (size_t)l * npoints + base + t);
        __syncthreads();

        f32x4* __restrict__ o = (f32x4*)(out + (size_t)base * 32);
#pragma unroll
        for (int k = 0; k < 8; ++k) {
            const int s = (k << 8) | t;   // xmm index within the block's 32 KB
            const int p = s >> 3;         // local point
            const int c = s & 7;          // 16 B chunk within the point's row
            const f32x2 a = tile[p][2 * c];
            const f32x2 b = tile[p][2 * c + 1];
            f32x4 q = { a.x, a.y, b.x, b.y };
            __builtin_nontemporal_store(q, o + s);
        }
    } else {
        // tail (npoints not a multiple of 256): per-point guarded path
        const int p = base + t;
        if (p < npoints) {
            f32x2 v[16];
#pragma unroll
            for (int l = 0; l < 16; ++l)
                v[l] = ws[(size_t)l * npoints + p];
            f32x4* orow = (f32x4*)(out + (size_t)p * 32);
#pragma unroll
            for (int i = 0; i < 8; ++i) {
                f32x4 q = { v[2 * i].x, v[2 * i].y, v[2 * i + 1].x, v[2 * i + 1].y };
                orow[i] = q;
            }
        }
    }
}

// ---------------- Fallback (round-3 kernel) if ws too small ----------------
__global__ __launch_bounds__(256) void hashgrid_fallback_kernel(
    const float* __restrict__ x,
    const float* __restrict__ tables,
    float* __restrict__ out)
{
    const int p = blockIdx.x * 256 + threadIdx.x;

    const float px = x[3 * p + 0] + 1.0f;
    const float py = x[3 * p + 1] + 1.0f;
    const float pz = x[3 * p + 2] + 1.0f;

    float acc[32];
    const float2* __restrict__ tab = (const float2*)tables;

#pragma unroll
    for (int l = 0; l < 16; ++l) {
        const float halfr = 0.5f * RES_C[l];
        const float fx = px * halfr, fy = py * halfr, fz = pz * halfr;
        const float bx = floorf(fx), by = floorf(fy), bz = floorf(fz);
        const float wx = fx - bx, wy = fy - by, wz = fz - bz;

        const unsigned ix0 = (unsigned)(int)bx;
        const unsigned iy0 = (unsigned)(int)by * P1;
        const unsigned iz0 = (unsigned)(int)bz * P2;
        const unsigned ix1 = ix0 + 1u, iy1 = iy0 + P1, iz1 = iz0 + P2;
        const unsigned base = (unsigned)l * TSIZE;

        const float2 v000 = tab[base + ((ix0 ^ iy0 ^ iz0) & HMASK)];
        const float2 v001 = tab[base + ((ix0 ^ iy0 ^ iz1) & HMASK)];
        const float2 v010 = tab[base + ((ix0 ^ iy1 ^ iz0) & HMASK)];
        const float2 v011 = tab[base + ((ix0 ^ iy1 ^ iz1) & HMASK)];
        const float2 v100 = tab[base + ((ix1 ^ iy0 ^ iz0) & HMASK)];
        const float2 v101 = tab[base + ((ix1 ^ iy0 ^ iz1) & HMASK)];
        const float2 v110 = tab[base + ((ix1 ^ iy1 ^ iz0) & HMASK)];
        const float2 v111 = tab[base + ((ix1 ^ iy1 ^ iz1) & HMASK)];

        const float c00a = v000.x + wx * (v100.x - v000.x);
        const float c00b = v000.y + wx * (v100.y - v000.y);
        const float c01a = v001.x + wx * (v101.x - v001.x);
        const float c01b = v001.y + wx * (v101.y - v001.y);
        const float c10a = v010.x + wx * (v110.x - v010.x);
        const float c10b = v010.y + wx * (v110.y - v010.y);
        const float c11a = v011.x + wx * (v111.x - v011.x);
        const float c11b = v011.y + wx * (v111.y - v011.y);

        const float c0a = c00a + wy * (c10a - c00a);
        const float c0b = c00b + wy * (c10b - c00b);
        const float c1a = c01a + wy * (c11a - c01a);
        const float c1b = c01b + wy * (c11b - c01b);

        acc[2 * l + 0] = c0a + wz * (c1a - c0a);
        acc[2 * l + 1] = c0b + wz * (c1b - c0b);
    }

    f32x4* orow = (f32x4*)(out + (size_t)p * 32);
#pragma unroll
    for (int i = 0; i < 8; ++i) {
        f32x4 v = { acc[4 * i + 0], acc[4 * i + 1], acc[4 * i + 2], acc[4 * i + 3] };
        orow[i] = v;
    }
}

extern "C" void kernel_launch(void* const* d_in, const int* in_sizes, int n_in,
                              void* d_out, int out_size, void* d_ws, size_t ws_size,
                              hipStream_t stream) {
    const float* x      = (const float*)d_in[0];
    const float* tables = (const float*)d_in[1];
    float* out          = (float*)d_out;

    const int npoints = in_sizes[0] / 3;                       // 1048576
    const size_t ws_needed = (size_t)16 * npoints * sizeof(float2);  // 128 MB

    if (ws_size >= ws_needed) {
        // chunks per level: ceil(npoints/512) rounded up to power of two
        int chunks = (npoints + 511) / 512;
        int levelShift = 0;
        while ((1 << levelShift) < chunks) ++levelShift;

        dim3 blockA(256);
        dim3 gridA(16 << levelShift);
        hipLaunchKernelGGL(gather_level_kernel, gridA, blockA, 0, stream,
                           x, tables, (f32x2*)d_ws, npoints, levelShift);

        dim3 blockB(256);
        dim3 gridB((npoints + 255) / 256);
        hipLaunchKernelGGL(transpose_lds_kernel, gridB, blockB, 0, stream,
                           (const f32x2*)d_ws, out, npoints);
    } else {
        dim3 block(256);
        dim3 grid((npoints + 255) / 256);
        hipLaunchKernelGGL(hashgrid_fallback_kernel, grid, block, 0, stream,
                           x, tables, out);
    }
}